// Round 1
// 2400.392 us; speedup vs baseline: 3.0406x; 3.0406x over previous
//
#include <hip/hip_runtime.h>
#include <cstdint>
#include <cstddef>

typedef unsigned short u16;

#define F_DIM   128
#define HF_DIM  512
#define NRBF    20
#define NOUT    384

using bf16x8 = __attribute__((ext_vector_type(8))) __bf16;
using f32x4  = __attribute__((ext_vector_type(4))) float;

__device__ __forceinline__ float bf2f(u16 u){
    union { unsigned int i; float f; } v; v.i = ((unsigned int)u) << 16; return v.f;
}
__device__ __forceinline__ u16 f2bf(float f){
    union { float f; unsigned int i; } v; v.f = f;
    unsigned int x = v.i;
    unsigned int r = x + 0x7fffu + ((x >> 16) & 1u);   // RTNE
    return (u16)(r >> 16);
}
__device__ __forceinline__ float silu(float x){
    return x * __fdividef(1.0f, 1.0f + __expf(-x));
}

// ---------------------------------------------------------------------------
// S0: pack denseW (512x384 f32) -> bf16 in MFMA B-fragment order.
// Bp[(((nt*16 + ks)*64 + lane)*8 + j] = bf16( dW[(ks*32 + (lane>>4)*8 + j)*384
//                                              + nt*16 + (lane&15)] )
// 24 n-tiles x 16 k-steps x 64 lanes x 8 elems = 196608 elems (393 KB, L2-fit).
// ---------------------------------------------------------------------------
__global__ __launch_bounds__(256) void s0_packW(
    const float* __restrict__ dW, u16* __restrict__ Bp)
{
    const int t = blockIdx.x * 256 + threadIdx.x;
    if (t >= 24 * 16 * 64 * 8) return;
    const int j    = t & 7;
    const int lane = (t >> 3) & 63;
    const int ks   = (t >> 9) & 15;
    const int nt   = t >> 13;
    const int k = ks * 32 + ((lane >> 4) << 3) + j;
    const int n = nt * 16 + (lane & 15);
    Bp[t] = f2bf(dW[(size_t)k * NOUT + n]);
}

// ---------------------------------------------------------------------------
// S1: LayerNorm, literal. One block (128 threads) per node. f32 out.
// ---------------------------------------------------------------------------
__global__ __launch_bounds__(128) void s1_ln(
    const float* __restrict__ s_j, const float* __restrict__ ln_g,
    const float* __restrict__ ln_b, float* __restrict__ inp, int N)
{
    __shared__ float ps[2], pss[2];
    const int n = blockIdx.x;
    const int f = threadIdx.x;
    float x = s_j[(size_t)n * F_DIM + f];
    float s = x, ss = x * x;
    #pragma unroll
    for (int o = 1; o < 64; o <<= 1){
        s  += __shfl_xor(s,  o);
        ss += __shfl_xor(ss, o);
    }
    const int wid = f >> 6;
    if ((f & 63) == 0){ ps[wid] = s; pss[wid] = ss; }
    __syncthreads();
    const float S  = ps[0] + ps[1];
    const float SS = pss[0] + pss[1];
    const float mu  = S * (1.f / 128.f);
    const float var = SS * (1.f / 128.f) - mu * mu;
    const float r   = rsqrtf(var + 1e-5f);
    inp[(size_t)n * F_DIM + f] = (x - mu) * r * ln_g[f] + ln_b[f];
}

// ---------------------------------------------------------------------------
// S2: QKV projection, scalar. One block (512 threads) per node; thread = col.
// ---------------------------------------------------------------------------
__global__ __launch_bounds__(512) void s2_qkv(
    const float* __restrict__ inp,
    const float* __restrict__ Wq, const float* __restrict__ bq,
    const float* __restrict__ Wk, const float* __restrict__ bk,
    const float* __restrict__ Wv, const float* __restrict__ bv,
    u16* __restrict__ qo, u16* __restrict__ ko, u16* __restrict__ vo, int N)
{
    __shared__ float a[F_DIM];
    const int n = blockIdx.x;
    const int col = threadIdx.x;
    if (col < F_DIM) a[col] = inp[(size_t)n * F_DIM + col];
    __syncthreads();
    float aq = bq[col], ak = bk[col], av = bv[col];
    for (int k = 0; k < F_DIM; k++){
        const float x = a[k];
        aq += x * Wq[k * HF_DIM + col];
        ak += x * Wk[k * HF_DIM + col];
        av += x * Wv[k * HF_DIM + col];
    }
    qo[(size_t)n * HF_DIM + col] = f2bf(aq);
    ko[(size_t)n * HF_DIM + col] = f2bf(ak);
    vo[(size_t)n * HF_DIM + col] = f2bf(av);
}

// ---------------------------------------------------------------------------
// S3: fused edge pipeline + dense. Block = 32 edges, 256 threads (4 waves).
// Phase A: thread = (edge, head, half): rbf matvecs, attn, msg -> LDS (bf16).
// Phase B: MFMA 16x16x32 bf16. Wave w owns cols [w*96, w*96+96); acc[2][6]
//          fragments over 16 K-steps. B read from pre-packed L2-resident Bp.
// ---------------------------------------------------------------------------
__global__ __launch_bounds__(256) void s3_edge_dense(
    const float* __restrict__ dist, const int* __restrict__ nbrs,
    const u16* __restrict__ q_ws, const u16* __restrict__ k_ws, const u16* __restrict__ v_ws,
    const float* __restrict__ dkW, const float* __restrict__ dkb,
    const float* __restrict__ dvW, const float* __restrict__ dvb,
    const u16* __restrict__ Bp, const float* __restrict__ db,
    float* __restrict__ out, int E, int N)
{
    __shared__ __align__(16) u16 msg_s[32][520];   // row stride 1040B = 65*16B
    __shared__ float rbf_sh[32][21];
    __shared__ float env_sh[32];
    const int tid = threadIdx.x;
    const int e0 = blockIdx.x * 32;

    if (tid < 32){
        int de = e0 + tid; if (de >= E) de = E - 1;
        float d = dist[de];
        env_sh[tid] = 0.5f * (__cosf(0.62831853071f * d) + 1.0f);   // pi/5
        const float delta = 5.0f / 19.0f;   // CUTOFF/(N_RBF-1)
        const float invd  = 19.0f / 5.0f;
        #pragma unroll
        for (int r = 0; r < NRBF; r++){
            float t = (d - delta * (float)r) * invd;
            rbf_sh[tid][r] = __expf(-0.5f * t * t);
        }
    }
    __syncthreads();

    // ---- Phase A: build msg tile in LDS (bf16) ----
    {
        const int e_l = tid >> 3, sub = tid & 7;
        const int h = sub >> 1, half = sub & 1;
        const int fb = h * F_DIM + half * 64;          // this thread's 64 feats
        int e = e0 + e_l; if (e >= E) e = E - 1;
        int i_idx = nbrs[2*e + 0];
        int j_idx = nbrs[2*e + 1];
        i_idx = (i_idx < 0) ? 0 : (i_idx >= N ? N-1 : i_idx);
        j_idx = (j_idx < 0) ? 0 : (j_idx >= N ? N-1 : j_idx);
        float rbf[NRBF];
        #pragma unroll
        for (int r = 0; r < NRBF; r++) rbf[r] = rbf_sh[e_l][r];
        const float env = env_sh[e_l];
        const u16* qrow = q_ws + (size_t)i_idx * HF_DIM + fb;
        const u16* krow = k_ws + (size_t)j_idx * HF_DIM + fb;
        const u16* vrow = v_ws + (size_t)j_idx * HF_DIM + fb;

        float attn = 0.f;
        for (int c = 0; c < 8; c++){
            const int f0 = c * 8;
            float a8[8];
            #pragma unroll
            for (int j = 0; j < 8; j++) a8[j] = dkb[fb + f0 + j];
            #pragma unroll
            for (int r = 0; r < NRBF; r++){
                const float rv = rbf[r];
                const float* wp = dkW + (size_t)r * HF_DIM + fb + f0;
                #pragma unroll
                for (int j = 0; j < 8; j++) a8[j] += rv * wp[j];
            }
            uint4 qu = *(const uint4*)(qrow + f0);
            uint4 ku = *(const uint4*)(krow + f0);
            const u16* qp = (const u16*)&qu;
            const u16* kp = (const u16*)&ku;
            #pragma unroll
            for (int j = 0; j < 8; j++)
                attn += bf2f(qp[j]) * silu(a8[j]) * bf2f(kp[j]);
        }
        attn += __shfl_xor(attn, 1);                   // combine the two halves
        const float scale = silu(attn) * env;

        for (int c = 0; c < 8; c++){
            const int f0 = c * 8;
            float a8[8];
            #pragma unroll
            for (int j = 0; j < 8; j++) a8[j] = dvb[fb + f0 + j];
            #pragma unroll
            for (int r = 0; r < NRBF; r++){
                const float rv = rbf[r];
                const float* wp = dvW + (size_t)r * HF_DIM + fb + f0;
                #pragma unroll
                for (int j = 0; j < 8; j++) a8[j] += rv * wp[j];
            }
            uint4 vu = *(const uint4*)(vrow + f0);
            const u16* vp = (const u16*)&vu;
            u16 ov[8];
            #pragma unroll
            for (int j = 0; j < 8; j++)
                ov[j] = f2bf(scale * bf2f(vp[j]) * silu(a8[j]));
            *(uint4*)&msg_s[e_l][fb + f0] = *(const uint4*)ov;
        }
    }
    __syncthreads();

    // ---- Phase B: MFMA dense (M=32 edges, N=384, K=512) ----
    {
        const int lane = tid & 63;
        const int wave = tid >> 6;                 // wave w -> cols [w*96, w*96+96)
        const int am   = lane & 15;                // A row within 16-tile
        const int akb  = (lane >> 4) << 3;         // A k-offset within K=32 step
        const int cn   = lane & 15;                // C col within 16-tile
        const int cr0  = (lane >> 4) << 2;         // C row base (+reg)

        f32x4 acc[2][6];
        #pragma unroll
        for (int nt = 0; nt < 6; nt++){
            const float bias = db[wave * 96 + nt * 16 + cn];
            acc[0][nt] = (f32x4){bias, bias, bias, bias};
            acc[1][nt] = acc[0][nt];
        }

        const u16* bbase = Bp + (size_t)(wave * 6) * (16 * 64 * 8);

        #pragma unroll 4
        for (int ks = 0; ks < 16; ks++){
            const bf16x8 a0 = *(const bf16x8*)&msg_s[am]     [(ks << 5) + akb];
            const bf16x8 a1 = *(const bf16x8*)&msg_s[16 + am][(ks << 5) + akb];
            #pragma unroll
            for (int nt = 0; nt < 6; nt++){
                const bf16x8 b = *(const bf16x8*)(bbase + (((nt * 16 + ks) * 64 + lane) << 3));
                acc[0][nt] = __builtin_amdgcn_mfma_f32_16x16x32_bf16(a0, b, acc[0][nt], 0, 0, 0);
                acc[1][nt] = __builtin_amdgcn_mfma_f32_16x16x32_bf16(a1, b, acc[1][nt], 0, 0, 0);
            }
        }

        // C/D layout (m89-verified): col = lane&15, row = (lane>>4)*4 + reg
        #pragma unroll
        for (int mt = 0; mt < 2; mt++){
            #pragma unroll
            for (int r = 0; r < 4; r++){
                const int grow = e0 + mt * 16 + cr0 + r;
                if (grow < E){
                    float* op = out + (size_t)grow * NOUT + wave * 96 + cn;
                    #pragma unroll
                    for (int nt = 0; nt < 6; nt++)
                        op[nt * 16] = acc[mt][nt][r];
                }
            }
        }
    }
}

// ---------------------------------------------------------------------------
extern "C" void kernel_launch(void* const* d_in, const int* in_sizes, int n_in,
                              void* d_out, int out_size, void* d_ws, size_t ws_size,
                              hipStream_t stream)
{
    const float* s_j  = (const float*)d_in[0];
    const float* dist = (const float*)d_in[1];
    const int*   nbrs = (const int*)d_in[2];
    const float* ln_g = (const float*)d_in[3];
    const float* ln_b = (const float*)d_in[4];
    const float* Wq   = (const float*)d_in[5];
    const float* bq   = (const float*)d_in[6];
    const float* Wk   = (const float*)d_in[7];
    const float* bk   = (const float*)d_in[8];
    const float* Wv   = (const float*)d_in[9];
    const float* bv   = (const float*)d_in[10];
    const float* dkW  = (const float*)d_in[11];
    const float* dkb  = (const float*)d_in[12];
    const float* dvW  = (const float*)d_in[13];
    const float* dvb  = (const float*)d_in[14];
    const float* dW   = (const float*)d_in[15];
    const float* db   = (const float*)d_in[16];
    const int N = in_sizes[0] / F_DIM;
    const int E = in_sizes[1];
    (void)n_in; (void)out_size; (void)ws_size;

    char* ws = (char*)d_ws;
    size_t off = 0;
    auto walloc = [&](size_t bytes) -> void* {
        void* p = ws + off;
        off += (bytes + 255) & ~(size_t)255;
        return p;
    };
    float* inp_ws = (float*)walloc((size_t)N * F_DIM * 4);
    u16*   q_ws   = (u16*)walloc((size_t)N * HF_DIM * 2);
    u16*   k_ws   = (u16*)walloc((size_t)N * HF_DIM * 2);
    u16*   v_ws   = (u16*)walloc((size_t)N * HF_DIM * 2);
    u16*   Bp_ws  = (u16*)walloc((size_t)24 * 16 * 64 * 8 * 2);   // 393 KB

    s0_packW<<<768, 256, 0, stream>>>(dW, Bp_ws);
    s1_ln<<<N, 128, 0, stream>>>(s_j, ln_g, ln_b, inp_ws, N);
    s2_qkv<<<N, 512, 0, stream>>>(inp_ws, Wq, bq, Wk, bk, Wv, bv,
                                  q_ws, k_ws, v_ws, N);
    s3_edge_dense<<<(E + 31)/32, 256, 0, stream>>>(
        dist, nbrs, q_ws, k_ws, v_ws,
        dkW, dkb, dvW, dvb, Bp_ws, db, (float*)d_out, E, N);
}

// Round 2
// 2092.548 us; speedup vs baseline: 3.4880x; 1.1471x over previous
//
#include <hip/hip_runtime.h>
#include <cstdint>
#include <cstddef>

typedef unsigned short u16;

#define F_DIM   128
#define HF_DIM  512
#define NRBF    20
#define NOUT    384

using bf16x8 = __attribute__((ext_vector_type(8))) __bf16;
using f32x4  = __attribute__((ext_vector_type(4))) float;

__device__ __forceinline__ float bf2f(u16 u){
    union { unsigned int i; float f; } v; v.i = ((unsigned int)u) << 16; return v.f;
}
__device__ __forceinline__ u16 f2bf(float f){
    union { float f; unsigned int i; } v; v.f = f;
    unsigned int x = v.i;
    unsigned int r = x + 0x7fffu + ((x >> 16) & 1u);   // RTNE
    return (u16)(r >> 16);
}
__device__ __forceinline__ float silu(float x){
    return x * __fdividef(1.0f, 1.0f + __expf(-x));
}

// ---------------------------------------------------------------------------
// S0: pack denseW (512x384 f32) -> bf16 in MFMA B-fragment order.
// Bp[((nt*16 + ks)*64 + lane)*8 + j] = bf16( dW[(ks*32 + (lane>>4)*8 + j)*384
//                                             + nt*16 + (lane&15)] )
// ---------------------------------------------------------------------------
__global__ __launch_bounds__(256) void s0_packW(
    const float* __restrict__ dW, u16* __restrict__ Bp)
{
    const int t = blockIdx.x * 256 + threadIdx.x;
    if (t >= 24 * 16 * 64 * 8) return;
    const int j    = t & 7;
    const int lane = (t >> 3) & 63;
    const int ks   = (t >> 9) & 15;
    const int nt   = t >> 13;
    const int k = ks * 32 + ((lane >> 4) << 3) + j;
    const int n = nt * 16 + (lane & 15);
    Bp[t] = f2bf(dW[(size_t)k * NOUT + n]);
}

// ---------------------------------------------------------------------------
// S1: LayerNorm. One block (128 threads) per node. f32 out.
// ---------------------------------------------------------------------------
__global__ __launch_bounds__(128) void s1_ln(
    const float* __restrict__ s_j, const float* __restrict__ ln_g,
    const float* __restrict__ ln_b, float* __restrict__ inp, int N)
{
    __shared__ float ps[2], pss[2];
    const int n = blockIdx.x;
    const int f = threadIdx.x;
    float x = s_j[(size_t)n * F_DIM + f];
    float s = x, ss = x * x;
    #pragma unroll
    for (int o = 1; o < 64; o <<= 1){
        s  += __shfl_xor(s,  o);
        ss += __shfl_xor(ss, o);
    }
    const int wid = f >> 6;
    if ((f & 63) == 0){ ps[wid] = s; pss[wid] = ss; }
    __syncthreads();
    const float S  = ps[0] + ps[1];
    const float SS = pss[0] + pss[1];
    const float mu  = S * (1.f / 128.f);
    const float var = SS * (1.f / 128.f) - mu * mu;
    const float r   = rsqrtf(var + 1e-5f);
    inp[(size_t)n * F_DIM + f] = (x - mu) * r * ln_g[f] + ln_b[f];
}

// ---------------------------------------------------------------------------
// S2: QKV projection, node-tiled + register-blocked.
// Block = 16 nodes, 256 threads; thread t owns cols (2t, 2t+1) of q,k,v.
// Weight L2 traffic: 768KB per 16 nodes (was per 1 node) = 16x cut.
// ---------------------------------------------------------------------------
#define S2_NT 16
__device__ __forceinline__ void s2_mat(
    const float (*a_s)[F_DIM], const float* __restrict__ W,
    const float* __restrict__ b, u16* __restrict__ o, int n0, int c0)
{
    float acc0[S2_NT], acc1[S2_NT];
    const float b0 = b[c0], b1 = b[c0 + 1];
    #pragma unroll
    for (int n = 0; n < S2_NT; n++){ acc0[n] = b0; acc1[n] = b1; }
    for (int k = 0; k < F_DIM; k += 4){
        const float2 w0 = *(const float2*)(W + (size_t)(k+0) * HF_DIM + c0);
        const float2 w1 = *(const float2*)(W + (size_t)(k+1) * HF_DIM + c0);
        const float2 w2 = *(const float2*)(W + (size_t)(k+2) * HF_DIM + c0);
        const float2 w3 = *(const float2*)(W + (size_t)(k+3) * HF_DIM + c0);
        #pragma unroll
        for (int n = 0; n < S2_NT; n++){
            const float4 av = *(const float4*)&a_s[n][k];
            acc0[n] += av.x*w0.x + av.y*w1.x + av.z*w2.x + av.w*w3.x;
            acc1[n] += av.x*w0.y + av.y*w1.y + av.z*w2.y + av.w*w3.y;
        }
    }
    #pragma unroll
    for (int n = 0; n < S2_NT; n++){
        const unsigned int pack =
            (unsigned int)f2bf(acc0[n]) | ((unsigned int)f2bf(acc1[n]) << 16);
        *(unsigned int*)(o + (size_t)(n0 + n) * HF_DIM + c0) = pack;
    }
}

__global__ __launch_bounds__(256) void s2_qkv_t(
    const float* __restrict__ inp,
    const float* __restrict__ Wq, const float* __restrict__ bq,
    const float* __restrict__ Wk, const float* __restrict__ bk,
    const float* __restrict__ Wv, const float* __restrict__ bv,
    u16* __restrict__ qo, u16* __restrict__ ko, u16* __restrict__ vo, int N)
{
    __shared__ float a_s[S2_NT][F_DIM];           // 8 KB
    const int tid = threadIdx.x;
    const int n0 = blockIdx.x * S2_NT;
    for (int i = tid; i < S2_NT * F_DIM / 4; i += 256)
        ((float4*)a_s)[i] = ((const float4*)(inp + (size_t)n0 * F_DIM))[i];
    __syncthreads();
    const int c0 = tid * 2;                        // 0..510
    s2_mat(a_s, Wq, bq, qo, n0, c0);
    s2_mat(a_s, Wk, bk, ko, n0, c0);
    s2_mat(a_s, Wv, bv, vo, n0, c0);
}

// ---------------------------------------------------------------------------
// S3a: edge message kernel (Phase A standalone). Block = 32 edges, 256 thr.
// Thread = (edge, head, half): rbf matvecs, attn, msg -> GLOBAL bf16.
// Tiny LDS -> occupancy VGPR-bound; gather loads hoisted above matvec.
// ---------------------------------------------------------------------------
__global__ __launch_bounds__(256) void s3a_edge_msg(
    const float* __restrict__ dist, const int* __restrict__ nbrs,
    const u16* __restrict__ q_ws, const u16* __restrict__ k_ws, const u16* __restrict__ v_ws,
    const float* __restrict__ dkW, const float* __restrict__ dkb,
    const float* __restrict__ dvW, const float* __restrict__ dvb,
    u16* __restrict__ msg_g, int E, int N)
{
    __shared__ float rbf_sh[32][21];
    __shared__ float env_sh[32];
    const int tid = threadIdx.x;
    const int e0 = blockIdx.x * 32;

    if (tid < 32){
        int de = e0 + tid; if (de >= E) de = E - 1;
        float d = dist[de];
        env_sh[tid] = 0.5f * (__cosf(0.62831853071f * d) + 1.0f);   // pi/5
        const float delta = 5.0f / 19.0f;
        const float invd  = 19.0f / 5.0f;
        #pragma unroll
        for (int r = 0; r < NRBF; r++){
            float t = (d - delta * (float)r) * invd;
            rbf_sh[tid][r] = __expf(-0.5f * t * t);
        }
    }
    __syncthreads();

    const int e_l = tid >> 3, sub = tid & 7;
    const int h = sub >> 1, half = sub & 1;
    const int fb = h * F_DIM + half * 64;          // this thread's 64 feats
    int e = e0 + e_l; if (e >= E) e = E - 1;
    int i_idx = nbrs[2*e + 0];
    int j_idx = nbrs[2*e + 1];
    i_idx = (i_idx < 0) ? 0 : (i_idx >= N ? N-1 : i_idx);
    j_idx = (j_idx < 0) ? 0 : (j_idx >= N ? N-1 : j_idx);
    float rbf[NRBF];
    #pragma unroll
    for (int r = 0; r < NRBF; r++) rbf[r] = rbf_sh[e_l][r];
    const float env = env_sh[e_l];
    const u16* qrow = q_ws + (size_t)i_idx * HF_DIM + fb;
    const u16* krow = k_ws + (size_t)j_idx * HF_DIM + fb;
    const u16* vrow = v_ws + (size_t)j_idx * HF_DIM + fb;
    u16* mrow = msg_g + (size_t)e * HF_DIM + fb;

    float attn = 0.f;
    for (int c = 0; c < 8; c++){
        const int f0 = c * 8;
        // gathers issued FIRST: ~320cy of matvec below covers their latency
        uint4 qu = *(const uint4*)(qrow + f0);
        uint4 ku = *(const uint4*)(krow + f0);
        float a8[8];
        #pragma unroll
        for (int j = 0; j < 8; j++) a8[j] = dkb[fb + f0 + j];
        #pragma unroll
        for (int r = 0; r < NRBF; r++){
            const float rv = rbf[r];
            const float* wp = dkW + (size_t)r * HF_DIM + fb + f0;
            #pragma unroll
            for (int j = 0; j < 8; j++) a8[j] += rv * wp[j];
        }
        const u16* qp = (const u16*)&qu;
        const u16* kp = (const u16*)&ku;
        #pragma unroll
        for (int j = 0; j < 8; j++)
            attn += bf2f(qp[j]) * silu(a8[j]) * bf2f(kp[j]);
    }
    attn += __shfl_xor(attn, 1);                   // combine the two halves
    const float scale = silu(attn) * env;

    for (int c = 0; c < 8; c++){
        const int f0 = c * 8;
        uint4 vu = *(const uint4*)(vrow + f0);     // hoisted above matvec
        float a8[8];
        #pragma unroll
        for (int j = 0; j < 8; j++) a8[j] = dvb[fb + f0 + j];
        #pragma unroll
        for (int r = 0; r < NRBF; r++){
            const float rv = rbf[r];
            const float* wp = dvW + (size_t)r * HF_DIM + fb + f0;
            #pragma unroll
            for (int j = 0; j < 8; j++) a8[j] += rv * wp[j];
        }
        const u16* vp = (const u16*)&vu;
        u16 ov[8];
        #pragma unroll
        for (int j = 0; j < 8; j++)
            ov[j] = f2bf(scale * bf2f(vp[j]) * silu(a8[j]));
        *(uint4*)(mrow + f0) = *(const uint4*)ov;
    }
}

// ---------------------------------------------------------------------------
// S3b: dense GEMM. msg (E x 512 bf16) @ Bp -> out (E x 384 f32) + bias.
// Block = 32 edges, 512 threads (8 waves); wave w -> cols [w*48, w*48+48).
// A staged in LDS [32][520] (1040B stride -> 2-way bank alias = free).
// ---------------------------------------------------------------------------
__global__ __launch_bounds__(512) void s3b_dense(
    const u16* __restrict__ msg_g, const u16* __restrict__ Bp,
    const float* __restrict__ db, float* __restrict__ out, int E)
{
    __shared__ __align__(16) u16 msg_s[32][520];
    const int tid = threadIdx.x;
    const int e0 = blockIdx.x * 32;

    for (int i = tid; i < 32 * 64; i += 512){
        const int row = i >> 6, ch = i & 63;
        int ge = e0 + row; if (ge >= E) ge = E - 1;
        const uint4 d = *(const uint4*)(msg_g + (size_t)ge * HF_DIM + ch * 8);
        *(uint4*)&msg_s[row][ch * 8] = d;
    }
    __syncthreads();

    const int lane = tid & 63;
    const int wave = tid >> 6;                 // 0..7 -> nt base wave*3
    const int am   = lane & 15;
    const int akb  = (lane >> 4) << 3;
    const int cn   = lane & 15;
    const int cr0  = (lane >> 4) << 2;

    f32x4 acc[2][3];
    #pragma unroll
    for (int nt = 0; nt < 3; nt++){
        const float bias = db[wave * 48 + nt * 16 + cn];
        acc[0][nt] = (f32x4){bias, bias, bias, bias};
        acc[1][nt] = acc[0][nt];
    }

    const u16* bbase = Bp + (size_t)(wave * 3) * (16 * 64 * 8);

    #pragma unroll 4
    for (int ks = 0; ks < 16; ks++){
        const bf16x8 a0 = *(const bf16x8*)&msg_s[am]     [(ks << 5) + akb];
        const bf16x8 a1 = *(const bf16x8*)&msg_s[16 + am][(ks << 5) + akb];
        #pragma unroll
        for (int nt = 0; nt < 3; nt++){
            const bf16x8 b = *(const bf16x8*)(bbase + (((nt * 16 + ks) * 64 + lane) << 3));
            acc[0][nt] = __builtin_amdgcn_mfma_f32_16x16x32_bf16(a0, b, acc[0][nt], 0, 0, 0);
            acc[1][nt] = __builtin_amdgcn_mfma_f32_16x16x32_bf16(a1, b, acc[1][nt], 0, 0, 0);
        }
    }

    // C/D layout (m89-verified): col = lane&15, row = (lane>>4)*4 + reg
    #pragma unroll
    for (int mt = 0; mt < 2; mt++){
        #pragma unroll
        for (int r = 0; r < 4; r++){
            const int grow = e0 + mt * 16 + cr0 + r;
            if (grow < E){
                float* op = out + (size_t)grow * NOUT + wave * 48 + cn;
                #pragma unroll
                for (int nt = 0; nt < 3; nt++)
                    op[nt * 16] = acc[mt][nt][r];
            }
        }
    }
}

// ---------------------------------------------------------------------------
// Fallback: fused edge pipeline + dense (round-1 kernel) if workspace is
// too small for the 164MB msg buffer.
// ---------------------------------------------------------------------------
__global__ __launch_bounds__(256) void s3_fused(
    const float* __restrict__ dist, const int* __restrict__ nbrs,
    const u16* __restrict__ q_ws, const u16* __restrict__ k_ws, const u16* __restrict__ v_ws,
    const float* __restrict__ dkW, const float* __restrict__ dkb,
    const float* __restrict__ dvW, const float* __restrict__ dvb,
    const u16* __restrict__ Bp, const float* __restrict__ db,
    float* __restrict__ out, int E, int N)
{
    __shared__ __align__(16) u16 msg_s[32][520];
    __shared__ float rbf_sh[32][21];
    __shared__ float env_sh[32];
    const int tid = threadIdx.x;
    const int e0 = blockIdx.x * 32;

    if (tid < 32){
        int de = e0 + tid; if (de >= E) de = E - 1;
        float d = dist[de];
        env_sh[tid] = 0.5f * (__cosf(0.62831853071f * d) + 1.0f);
        const float delta = 5.0f / 19.0f;
        const float invd  = 19.0f / 5.0f;
        #pragma unroll
        for (int r = 0; r < NRBF; r++){
            float t = (d - delta * (float)r) * invd;
            rbf_sh[tid][r] = __expf(-0.5f * t * t);
        }
    }
    __syncthreads();
    {
        const int e_l = tid >> 3, sub = tid & 7;
        const int h = sub >> 1, half = sub & 1;
        const int fb = h * F_DIM + half * 64;
        int e = e0 + e_l; if (e >= E) e = E - 1;
        int i_idx = nbrs[2*e + 0];
        int j_idx = nbrs[2*e + 1];
        i_idx = (i_idx < 0) ? 0 : (i_idx >= N ? N-1 : i_idx);
        j_idx = (j_idx < 0) ? 0 : (j_idx >= N ? N-1 : j_idx);
        float rbf[NRBF];
        #pragma unroll
        for (int r = 0; r < NRBF; r++) rbf[r] = rbf_sh[e_l][r];
        const float env = env_sh[e_l];
        const u16* qrow = q_ws + (size_t)i_idx * HF_DIM + fb;
        const u16* krow = k_ws + (size_t)j_idx * HF_DIM + fb;
        const u16* vrow = v_ws + (size_t)j_idx * HF_DIM + fb;

        float attn = 0.f;
        for (int c = 0; c < 8; c++){
            const int f0 = c * 8;
            uint4 qu = *(const uint4*)(qrow + f0);
            uint4 ku = *(const uint4*)(krow + f0);
            float a8[8];
            #pragma unroll
            for (int j = 0; j < 8; j++) a8[j] = dkb[fb + f0 + j];
            #pragma unroll
            for (int r = 0; r < NRBF; r++){
                const float rv = rbf[r];
                const float* wp = dkW + (size_t)r * HF_DIM + fb + f0;
                #pragma unroll
                for (int j = 0; j < 8; j++) a8[j] += rv * wp[j];
            }
            const u16* qp = (const u16*)&qu;
            const u16* kp = (const u16*)&ku;
            #pragma unroll
            for (int j = 0; j < 8; j++)
                attn += bf2f(qp[j]) * silu(a8[j]) * bf2f(kp[j]);
        }
        attn += __shfl_xor(attn, 1);
        const float scale = silu(attn) * env;

        for (int c = 0; c < 8; c++){
            const int f0 = c * 8;
            uint4 vu = *(const uint4*)(vrow + f0);
            float a8[8];
            #pragma unroll
            for (int j = 0; j < 8; j++) a8[j] = dvb[fb + f0 + j];
            #pragma unroll
            for (int r = 0; r < NRBF; r++){
                const float rv = rbf[r];
                const float* wp = dvW + (size_t)r * HF_DIM + fb + f0;
                #pragma unroll
                for (int j = 0; j < 8; j++) a8[j] += rv * wp[j];
            }
            const u16* vp = (const u16*)&vu;
            u16 ov[8];
            #pragma unroll
            for (int j = 0; j < 8; j++)
                ov[j] = f2bf(scale * bf2f(vp[j]) * silu(a8[j]));
            *(uint4*)&msg_s[e_l][fb + f0] = *(const uint4*)ov;
        }
    }
    __syncthreads();
    {
        const int lane = tid & 63;
        const int wave = tid >> 6;
        const int am   = lane & 15;
        const int akb  = (lane >> 4) << 3;
        const int cn   = lane & 15;
        const int cr0  = (lane >> 4) << 2;

        f32x4 acc[2][6];
        #pragma unroll
        for (int nt = 0; nt < 6; nt++){
            const float bias = db[wave * 96 + nt * 16 + cn];
            acc[0][nt] = (f32x4){bias, bias, bias, bias};
            acc[1][nt] = acc[0][nt];
        }
        const u16* bbase = Bp + (size_t)(wave * 6) * (16 * 64 * 8);
        #pragma unroll 4
        for (int ks = 0; ks < 16; ks++){
            const bf16x8 a0 = *(const bf16x8*)&msg_s[am]     [(ks << 5) + akb];
            const bf16x8 a1 = *(const bf16x8*)&msg_s[16 + am][(ks << 5) + akb];
            #pragma unroll
            for (int nt = 0; nt < 6; nt++){
                const bf16x8 b = *(const bf16x8*)(bbase + (((nt * 16 + ks) * 64 + lane) << 3));
                acc[0][nt] = __builtin_amdgcn_mfma_f32_16x16x32_bf16(a0, b, acc[0][nt], 0, 0, 0);
                acc[1][nt] = __builtin_amdgcn_mfma_f32_16x16x32_bf16(a1, b, acc[1][nt], 0, 0, 0);
            }
        }
        #pragma unroll
        for (int mt = 0; mt < 2; mt++){
            #pragma unroll
            for (int r = 0; r < 4; r++){
                const int grow = e0 + mt * 16 + cr0 + r;
                if (grow < E){
                    float* op = out + (size_t)grow * NOUT + wave * 96 + cn;
                    #pragma unroll
                    for (int nt = 0; nt < 6; nt++)
                        op[nt * 16] = acc[mt][nt][r];
                }
            }
        }
    }
}

// ---------------------------------------------------------------------------
extern "C" void kernel_launch(void* const* d_in, const int* in_sizes, int n_in,
                              void* d_out, int out_size, void* d_ws, size_t ws_size,
                              hipStream_t stream)
{
    const float* s_j  = (const float*)d_in[0];
    const float* dist = (const float*)d_in[1];
    const int*   nbrs = (const int*)d_in[2];
    const float* ln_g = (const float*)d_in[3];
    const float* ln_b = (const float*)d_in[4];
    const float* Wq   = (const float*)d_in[5];
    const float* bq   = (const float*)d_in[6];
    const float* Wk   = (const float*)d_in[7];
    const float* bk   = (const float*)d_in[8];
    const float* Wv   = (const float*)d_in[9];
    const float* bv   = (const float*)d_in[10];
    const float* dkW  = (const float*)d_in[11];
    const float* dkb  = (const float*)d_in[12];
    const float* dvW  = (const float*)d_in[13];
    const float* dvb  = (const float*)d_in[14];
    const float* dW   = (const float*)d_in[15];
    const float* db   = (const float*)d_in[16];
    const int N = in_sizes[0] / F_DIM;
    const int E = in_sizes[1];
    (void)n_in; (void)out_size;

    char* ws = (char*)d_ws;
    size_t off = 0;
    auto walloc = [&](size_t bytes) -> void* {
        void* p = ws + off;
        off += (bytes + 255) & ~(size_t)255;
        return p;
    };
    float* inp_ws = (float*)walloc((size_t)N * F_DIM * 4);
    u16*   q_ws   = (u16*)walloc((size_t)N * HF_DIM * 2);
    u16*   k_ws   = (u16*)walloc((size_t)N * HF_DIM * 2);
    u16*   v_ws   = (u16*)walloc((size_t)N * HF_DIM * 2);
    u16*   Bp_ws  = (u16*)walloc((size_t)24 * 16 * 64 * 8 * 2);   // 393 KB
    const size_t off_base = off;
    u16*   msg_ws = (u16*)walloc((size_t)E * HF_DIM * 2);         // 164 MB
    const bool can_split = (ws_size >= off);
    (void)off_base;

    s0_packW<<<768, 256, 0, stream>>>(dW, Bp_ws);
    s1_ln<<<N, 128, 0, stream>>>(s_j, ln_g, ln_b, inp_ws, N);
    s2_qkv_t<<<(N + S2_NT - 1)/S2_NT, 256, 0, stream>>>(
        inp_ws, Wq, bq, Wk, bk, Wv, bv, q_ws, k_ws, v_ws, N);

    if (can_split){
        s3a_edge_msg<<<(E + 31)/32, 256, 0, stream>>>(
            dist, nbrs, q_ws, k_ws, v_ws,
            dkW, dkb, dvW, dvb, msg_ws, E, N);
        s3b_dense<<<(E + 31)/32, 512, 0, stream>>>(
            msg_ws, Bp_ws, db, (float*)d_out, E);
    } else {
        s3_fused<<<(E + 31)/32, 256, 0, stream>>>(
            dist, nbrs, q_ws, k_ws, v_ws,
            dkW, dkb, dvW, dvb, Bp_ws, db, (float*)d_out, E, N);
    }
}

// Round 5
// 2069.761 us; speedup vs baseline: 3.5264x; 1.0110x over previous
//
#include <hip/hip_runtime.h>
#include <cstdint>
#include <cstddef>

typedef unsigned short u16;

#define F_DIM   128
#define HF_DIM  512
#define NRBF    20
#define NOUT    384

using bf16x8 = __attribute__((ext_vector_type(8))) __bf16;
using f32x4  = __attribute__((ext_vector_type(4))) float;
using u32x4  = __attribute__((ext_vector_type(4))) unsigned int;   // native vec for nontemporal builtins

__device__ __forceinline__ float bf2f(u16 u){
    union { unsigned int i; float f; } v; v.i = ((unsigned int)u) << 16; return v.f;
}
__device__ __forceinline__ u16 f2bf(float f){
    union { float f; unsigned int i; } v; v.f = f;
    unsigned int x = v.i;
    unsigned int r = x + 0x7fffu + ((x >> 16) & 1u);   // RTNE
    return (u16)(r >> 16);
}
__device__ __forceinline__ float silu(float x){
    return x * __fdividef(1.0f, 1.0f + __expf(-x));
}

// ---------------------------------------------------------------------------
// S0: pack denseW (512x384 f32) -> bf16 in MFMA B-fragment order.
// ---------------------------------------------------------------------------
__global__ __launch_bounds__(256) void s0_packW(
    const float* __restrict__ dW, u16* __restrict__ Bp)
{
    const int t = blockIdx.x * 256 + threadIdx.x;
    if (t >= 24 * 16 * 64 * 8) return;
    const int j    = t & 7;
    const int lane = (t >> 3) & 63;
    const int ks   = (t >> 9) & 15;
    const int nt   = t >> 13;
    const int k = ks * 32 + ((lane >> 4) << 3) + j;
    const int n = nt * 16 + (lane & 15);
    Bp[t] = f2bf(dW[(size_t)k * NOUT + n]);
}

// ---------------------------------------------------------------------------
// S0b: transpose rbf weights [20][512] -> [512][20] so each output column's
// 20 weights are contiguous (immediate-offset loads in s3a, no addr VALU).
// ---------------------------------------------------------------------------
__global__ __launch_bounds__(256) void s0b_packRBF(
    const float* __restrict__ dkW, const float* __restrict__ dvW,
    float* __restrict__ dkp, float* __restrict__ dvp)
{
    const int t = blockIdx.x * 256 + threadIdx.x;
    if (t >= HF_DIM * NRBF) return;
    const int p = t / NRBF, r = t - p * NRBF;
    dkp[t] = dkW[(size_t)r * HF_DIM + p];
    dvp[t] = dvW[(size_t)r * HF_DIM + p];
}

// ---------------------------------------------------------------------------
// S1: LayerNorm. One block (128 threads) per node. f32 out.
// ---------------------------------------------------------------------------
__global__ __launch_bounds__(128) void s1_ln(
    const float* __restrict__ s_j, const float* __restrict__ ln_g,
    const float* __restrict__ ln_b, float* __restrict__ inp, int N)
{
    __shared__ float ps[2], pss[2];
    const int n = blockIdx.x;
    const int f = threadIdx.x;
    float x = s_j[(size_t)n * F_DIM + f];
    float s = x, ss = x * x;
    #pragma unroll
    for (int o = 1; o < 64; o <<= 1){
        s  += __shfl_xor(s,  o);
        ss += __shfl_xor(ss, o);
    }
    const int wid = f >> 6;
    if ((f & 63) == 0){ ps[wid] = s; pss[wid] = ss; }
    __syncthreads();
    const float S  = ps[0] + ps[1];
    const float SS = pss[0] + pss[1];
    const float mu  = S * (1.f / 128.f);
    const float var = SS * (1.f / 128.f) - mu * mu;
    const float r   = rsqrtf(var + 1e-5f);
    inp[(size_t)n * F_DIM + f] = (x - mu) * r * ln_g[f] + ln_b[f];
}

// ---------------------------------------------------------------------------
// S2: QKV projection, node-tiled + register-blocked.
// ---------------------------------------------------------------------------
#define S2_NT 16
__device__ __forceinline__ void s2_mat(
    const float (*a_s)[F_DIM], const float* __restrict__ W,
    const float* __restrict__ b, u16* __restrict__ o, int n0, int c0)
{
    float acc0[S2_NT], acc1[S2_NT];
    const float b0 = b[c0], b1 = b[c0 + 1];
    #pragma unroll
    for (int n = 0; n < S2_NT; n++){ acc0[n] = b0; acc1[n] = b1; }
    for (int k = 0; k < F_DIM; k += 4){
        const float2 w0 = *(const float2*)(W + (size_t)(k+0) * HF_DIM + c0);
        const float2 w1 = *(const float2*)(W + (size_t)(k+1) * HF_DIM + c0);
        const float2 w2 = *(const float2*)(W + (size_t)(k+2) * HF_DIM + c0);
        const float2 w3 = *(const float2*)(W + (size_t)(k+3) * HF_DIM + c0);
        #pragma unroll
        for (int n = 0; n < S2_NT; n++){
            const float4 av = *(const float4*)&a_s[n][k];
            acc0[n] += av.x*w0.x + av.y*w1.x + av.z*w2.x + av.w*w3.x;
            acc1[n] += av.x*w0.y + av.y*w1.y + av.z*w2.y + av.w*w3.y;
        }
    }
    #pragma unroll
    for (int n = 0; n < S2_NT; n++){
        const unsigned int pack =
            (unsigned int)f2bf(acc0[n]) | ((unsigned int)f2bf(acc1[n]) << 16);
        *(unsigned int*)(o + (size_t)(n0 + n) * HF_DIM + c0) = pack;
    }
}

__global__ __launch_bounds__(256) void s2_qkv_t(
    const float* __restrict__ inp,
    const float* __restrict__ Wq, const float* __restrict__ bq,
    const float* __restrict__ Wk, const float* __restrict__ bk,
    const float* __restrict__ Wv, const float* __restrict__ bv,
    u16* __restrict__ qo, u16* __restrict__ ko, u16* __restrict__ vo, int N)
{
    __shared__ float a_s[S2_NT][F_DIM];           // 8 KB
    const int tid = threadIdx.x;
    const int n0 = blockIdx.x * S2_NT;
    for (int i = tid; i < S2_NT * F_DIM / 4; i += 256)
        ((float4*)a_s)[i] = ((const float4*)(inp + (size_t)n0 * F_DIM))[i];
    __syncthreads();
    const int c0 = tid * 2;                        // 0..510
    s2_mat(a_s, Wq, bq, qo, n0, c0);
    s2_mat(a_s, Wk, bk, ko, n0, c0);
    s2_mat(a_s, Wv, bv, vo, n0, c0);
}

// ---------------------------------------------------------------------------
// S3a v2: edge message kernel. Block = 32 edges, 256 thr.
// Thread = (edge, head, half). Changes vs v1:
//  - ALL q,k gathers (16x16B) issued before the dk matvec; all v gathers
//    before the dv matvec -> one latency exposure instead of eight.
//  - rbf weights read from transposed dkp/dvp [512][20]: contiguous 640B
//    per (thread,c) -> immediate-offset dwordx4, no per-load address VALU.
//  - msg written with nontemporal stores (don't evict q/k/v from L3).
// ---------------------------------------------------------------------------
__global__ __launch_bounds__(256, 2) void s3a_edge_msg(
    const float* __restrict__ dist, const int* __restrict__ nbrs,
    const u16* __restrict__ q_ws, const u16* __restrict__ k_ws, const u16* __restrict__ v_ws,
    const float* __restrict__ dkp, const float* __restrict__ dkb,
    const float* __restrict__ dvp, const float* __restrict__ dvb,
    u16* __restrict__ msg_g, int E, int N)
{
    __shared__ float rbf_sh[32][21];
    __shared__ float env_sh[32];
    const int tid = threadIdx.x;
    const int e0 = blockIdx.x * 32;

    if (tid < 32){
        int de = e0 + tid; if (de >= E) de = E - 1;
        float d = dist[de];
        env_sh[tid] = 0.5f * (__cosf(0.62831853071f * d) + 1.0f);   // pi/5
        const float delta = 5.0f / 19.0f;
        const float invd  = 19.0f / 5.0f;
        #pragma unroll
        for (int r = 0; r < NRBF; r++){
            float t = (d - delta * (float)r) * invd;
            rbf_sh[tid][r] = __expf(-0.5f * t * t);
        }
    }
    __syncthreads();

    const int e_l = tid >> 3, sub = tid & 7;
    const int h = sub >> 1, half = sub & 1;
    const int fb = h * F_DIM + half * 64;          // this thread's 64 feats
    int e = e0 + e_l; if (e >= E) e = E - 1;
    int i_idx = nbrs[2*e + 0];
    int j_idx = nbrs[2*e + 1];
    i_idx = (i_idx < 0) ? 0 : (i_idx >= N ? N-1 : i_idx);
    j_idx = (j_idx < 0) ? 0 : (j_idx >= N ? N-1 : j_idx);
    float rbf[NRBF];
    #pragma unroll
    for (int r = 0; r < NRBF; r++) rbf[r] = rbf_sh[e_l][r];
    const float env = env_sh[e_l];
    const u16* qrow = q_ws + (size_t)i_idx * HF_DIM + fb;
    const u16* krow = k_ws + (size_t)j_idx * HF_DIM + fb;
    const u16* vrow = v_ws + (size_t)j_idx * HF_DIM + fb;
    u16* mrow = msg_g + (size_t)e * HF_DIM + fb;

    const float* wkb = dkp + (size_t)fb * NRBF;    // this thread's 64x20 block
    const float* wvb = dvp + (size_t)fb * NRBF;

    // ---- issue ALL q,k gathers up front (16 independent loads in flight) --
    u32x4 qu[8], ku[8];
    #pragma unroll
    for (int c = 0; c < 8; c++) qu[c] = *(const u32x4*)(qrow + c * 8);
    #pragma unroll
    for (int c = 0; c < 8; c++) ku[c] = *(const u32x4*)(krow + c * 8);

    float attn = 0.f;
    #pragma unroll
    for (int c = 0; c < 8; c++){
        const int f0 = c * 8;
        float a8[8];
        #pragma unroll
        for (int j = 0; j < 8; j++) a8[j] = dkb[fb + f0 + j];
        #pragma unroll
        for (int j = 0; j < 8; j++){
            const float* wp = wkb + (f0 + j) * NRBF;   // 80B contiguous
            #pragma unroll
            for (int r = 0; r < NRBF; r++) a8[j] += rbf[r] * wp[r];
        }
        const u16* qp = (const u16*)&qu[c];
        const u16* kp = (const u16*)&ku[c];
        #pragma unroll
        for (int j = 0; j < 8; j++)
            attn += bf2f(qp[j]) * silu(a8[j]) * bf2f(kp[j]);
    }
    attn += __shfl_xor(attn, 1);                   // combine the two halves
    const float scale = silu(attn) * env;

    // ---- issue ALL v gathers, then dv matvec + store (nontemporal) -------
    u32x4 vu[8];
    #pragma unroll
    for (int c = 0; c < 8; c++) vu[c] = *(const u32x4*)(vrow + c * 8);

    #pragma unroll
    for (int c = 0; c < 8; c++){
        const int f0 = c * 8;
        float a8[8];
        #pragma unroll
        for (int j = 0; j < 8; j++) a8[j] = dvb[fb + f0 + j];
        #pragma unroll
        for (int j = 0; j < 8; j++){
            const float* wp = wvb + (f0 + j) * NRBF;
            #pragma unroll
            for (int r = 0; r < NRBF; r++) a8[j] += rbf[r] * wp[r];
        }
        const u16* vp = (const u16*)&vu[c];
        u16 ov[8];
        #pragma unroll
        for (int j = 0; j < 8; j++)
            ov[j] = f2bf(scale * bf2f(vp[j]) * silu(a8[j]));
        __builtin_nontemporal_store(*(const u32x4*)ov, (u32x4*)(mrow + f0));
    }
}

// ---------------------------------------------------------------------------
// S3b: dense GEMM. msg (E x 512 bf16) @ Bp -> out (E x 384 f32) + bias.
// msg read nontemporal (read-once), out stored nontemporal (write-once).
// ---------------------------------------------------------------------------
__global__ __launch_bounds__(512) void s3b_dense(
    const u16* __restrict__ msg_g, const u16* __restrict__ Bp,
    const float* __restrict__ db, float* __restrict__ out, int E)
{
    __shared__ __align__(16) u16 msg_s[32][520];
    const int tid = threadIdx.x;
    const int e0 = blockIdx.x * 32;

    for (int i = tid; i < 32 * 64; i += 512){
        const int row = i >> 6, ch = i & 63;
        int ge = e0 + row; if (ge >= E) ge = E - 1;
        const u32x4 d = __builtin_nontemporal_load(
            (const u32x4*)(msg_g + (size_t)ge * HF_DIM + ch * 8));
        *(u32x4*)&msg_s[row][ch * 8] = d;
    }
    __syncthreads();

    const int lane = tid & 63;
    const int wave = tid >> 6;                 // 0..7 -> nt base wave*3
    const int am   = lane & 15;
    const int akb  = (lane >> 4) << 3;
    const int cn   = lane & 15;
    const int cr0  = (lane >> 4) << 2;

    f32x4 acc[2][3];
    #pragma unroll
    for (int nt = 0; nt < 3; nt++){
        const float bias = db[wave * 48 + nt * 16 + cn];
        acc[0][nt] = (f32x4){bias, bias, bias, bias};
        acc[1][nt] = acc[0][nt];
    }

    const u16* bbase = Bp + (size_t)(wave * 3) * (16 * 64 * 8);

    #pragma unroll 4
    for (int ks = 0; ks < 16; ks++){
        const bf16x8 a0 = *(const bf16x8*)&msg_s[am]     [(ks << 5) + akb];
        const bf16x8 a1 = *(const bf16x8*)&msg_s[16 + am][(ks << 5) + akb];
        #pragma unroll
        for (int nt = 0; nt < 3; nt++){
            const bf16x8 b = *(const bf16x8*)(bbase + (((nt * 16 + ks) * 64 + lane) << 3));
            acc[0][nt] = __builtin_amdgcn_mfma_f32_16x16x32_bf16(a0, b, acc[0][nt], 0, 0, 0);
            acc[1][nt] = __builtin_amdgcn_mfma_f32_16x16x32_bf16(a1, b, acc[1][nt], 0, 0, 0);
        }
    }

    // C/D layout (m89-verified): col = lane&15, row = (lane>>4)*4 + reg
    #pragma unroll
    for (int mt = 0; mt < 2; mt++){
        #pragma unroll
        for (int r = 0; r < 4; r++){
            const int grow = e0 + mt * 16 + cr0 + r;
            if (grow < E){
                float* op = out + (size_t)grow * NOUT + wave * 48 + cn;
                #pragma unroll
                for (int nt = 0; nt < 3; nt++)
                    __builtin_nontemporal_store(acc[mt][nt][r], op + nt * 16);
            }
        }
    }
}

// ---------------------------------------------------------------------------
// Fallback: fused edge pipeline + dense if workspace is too small for the
// msg buffer. Uses original (untransposed) weight layout.
// ---------------------------------------------------------------------------
__global__ __launch_bounds__(256) void s3_fused(
    const float* __restrict__ dist, const int* __restrict__ nbrs,
    const u16* __restrict__ q_ws, const u16* __restrict__ k_ws, const u16* __restrict__ v_ws,
    const float* __restrict__ dkW, const float* __restrict__ dkb,
    const float* __restrict__ dvW, const float* __restrict__ dvb,
    const u16* __restrict__ Bp, const float* __restrict__ db,
    float* __restrict__ out, int E, int N)
{
    __shared__ __align__(16) u16 msg_s[32][520];
    __shared__ float rbf_sh[32][21];
    __shared__ float env_sh[32];
    const int tid = threadIdx.x;
    const int e0 = blockIdx.x * 32;

    if (tid < 32){
        int de = e0 + tid; if (de >= E) de = E - 1;
        float d = dist[de];
        env_sh[tid] = 0.5f * (__cosf(0.62831853071f * d) + 1.0f);
        const float delta = 5.0f / 19.0f;
        const float invd  = 19.0f / 5.0f;
        #pragma unroll
        for (int r = 0; r < NRBF; r++){
            float t = (d - delta * (float)r) * invd;
            rbf_sh[tid][r] = __expf(-0.5f * t * t);
        }
    }
    __syncthreads();
    {
        const int e_l = tid >> 3, sub = tid & 7;
        const int h = sub >> 1, half = sub & 1;
        const int fb = h * F_DIM + half * 64;
        int e = e0 + e_l; if (e >= E) e = E - 1;
        int i_idx = nbrs[2*e + 0];
        int j_idx = nbrs[2*e + 1];
        i_idx = (i_idx < 0) ? 0 : (i_idx >= N ? N-1 : i_idx);
        j_idx = (j_idx < 0) ? 0 : (j_idx >= N ? N-1 : j_idx);
        float rbf[NRBF];
        #pragma unroll
        for (int r = 0; r < NRBF; r++) rbf[r] = rbf_sh[e_l][r];
        const float env = env_sh[e_l];
        const u16* qrow = q_ws + (size_t)i_idx * HF_DIM + fb;
        const u16* krow = k_ws + (size_t)j_idx * HF_DIM + fb;
        const u16* vrow = v_ws + (size_t)j_idx * HF_DIM + fb;

        float attn = 0.f;
        for (int c = 0; c < 8; c++){
            const int f0 = c * 8;
            u32x4 qu = *(const u32x4*)(qrow + f0);
            u32x4 ku = *(const u32x4*)(krow + f0);
            float a8[8];
            #pragma unroll
            for (int j = 0; j < 8; j++) a8[j] = dkb[fb + f0 + j];
            #pragma unroll
            for (int r = 0; r < NRBF; r++){
                const float rv = rbf[r];
                const float* wp = dkW + (size_t)r * HF_DIM + fb + f0;
                #pragma unroll
                for (int j = 0; j < 8; j++) a8[j] += rv * wp[j];
            }
            const u16* qp = (const u16*)&qu;
            const u16* kp = (const u16*)&ku;
            #pragma unroll
            for (int j = 0; j < 8; j++)
                attn += bf2f(qp[j]) * silu(a8[j]) * bf2f(kp[j]);
        }
        attn += __shfl_xor(attn, 1);
        const float scale = silu(attn) * env;

        for (int c = 0; c < 8; c++){
            const int f0 = c * 8;
            u32x4 vu = *(const u32x4*)(vrow + f0);
            float a8[8];
            #pragma unroll
            for (int j = 0; j < 8; j++) a8[j] = dvb[fb + f0 + j];
            #pragma unroll
            for (int r = 0; r < NRBF; r++){
                const float rv = rbf[r];
                const float* wp = dvW + (size_t)r * HF_DIM + fb + f0;
                #pragma unroll
                for (int j = 0; j < 8; j++) a8[j] += rv * wp[j];
            }
            const u16* vp = (const u16*)&vu;
            u16 ov[8];
            #pragma unroll
            for (int j = 0; j < 8; j++)
                ov[j] = f2bf(scale * bf2f(vp[j]) * silu(a8[j]));
            *(u32x4*)&msg_s[e_l][fb + f0] = *(const u32x4*)ov;
        }
    }
    __syncthreads();
    {
        const int lane = tid & 63;
        const int wave = tid >> 6;
        const int am   = lane & 15;
        const int akb  = (lane >> 4) << 3;
        const int cn   = lane & 15;
        const int cr0  = (lane >> 4) << 2;

        f32x4 acc[2][6];
        #pragma unroll
        for (int nt = 0; nt < 6; nt++){
            const float bias = db[wave * 96 + nt * 16 + cn];
            acc[0][nt] = (f32x4){bias, bias, bias, bias};
            acc[1][nt] = acc[0][nt];
        }
        const u16* bbase = Bp + (size_t)(wave * 6) * (16 * 64 * 8);
        #pragma unroll 4
        for (int ks = 0; ks < 16; ks++){
            const bf16x8 a0 = *(const bf16x8*)&msg_s[am]     [(ks << 5) + akb];
            const bf16x8 a1 = *(const bf16x8*)&msg_s[16 + am][(ks << 5) + akb];
            #pragma unroll
            for (int nt = 0; nt < 6; nt++){
                const bf16x8 b = *(const bf16x8*)(bbase + (((nt * 16 + ks) * 64 + lane) << 3));
                acc[0][nt] = __builtin_amdgcn_mfma_f32_16x16x32_bf16(a0, b, acc[0][nt], 0, 0, 0);
                acc[1][nt] = __builtin_amdgcn_mfma_f32_16x16x32_bf16(a1, b, acc[1][nt], 0, 0, 0);
            }
        }
        #pragma unroll
        for (int mt = 0; mt < 2; mt++){
            #pragma unroll
            for (int r = 0; r < 4; r++){
                const int grow = e0 + mt * 16 + cr0 + r;
                if (grow < E){
                    float* op = out + (size_t)grow * NOUT + wave * 96 + cn;
                    #pragma unroll
                    for (int nt = 0; nt < 6; nt++)
                        op[nt * 16] = acc[mt][nt][r];
                }
            }
        }
    }
}

// ---------------------------------------------------------------------------
extern "C" void kernel_launch(void* const* d_in, const int* in_sizes, int n_in,
                              void* d_out, int out_size, void* d_ws, size_t ws_size,
                              hipStream_t stream)
{
    const float* s_j  = (const float*)d_in[0];
    const float* dist = (const float*)d_in[1];
    const int*   nbrs = (const int*)d_in[2];
    const float* ln_g = (const float*)d_in[3];
    const float* ln_b = (const float*)d_in[4];
    const float* Wq   = (const float*)d_in[5];
    const float* bq   = (const float*)d_in[6];
    const float* Wk   = (const float*)d_in[7];
    const float* bk   = (const float*)d_in[8];
    const float* Wv   = (const float*)d_in[9];
    const float* bv   = (const float*)d_in[10];
    const float* dkW  = (const float*)d_in[11];
    const float* dkb  = (const float*)d_in[12];
    const float* dvW  = (const float*)d_in[13];
    const float* dvb  = (const float*)d_in[14];
    const float* dW   = (const float*)d_in[15];
    const float* db   = (const float*)d_in[16];
    const int N = in_sizes[0] / F_DIM;
    const int E = in_sizes[1];
    (void)n_in; (void)out_size;

    char* ws = (char*)d_ws;
    size_t off = 0;
    auto walloc = [&](size_t bytes) -> void* {
        void* p = ws + off;
        off += (bytes + 255) & ~(size_t)255;
        return p;
    };
    float* inp_ws = (float*)walloc((size_t)N * F_DIM * 4);
    u16*   q_ws   = (u16*)walloc((size_t)N * HF_DIM * 2);
    u16*   k_ws   = (u16*)walloc((size_t)N * HF_DIM * 2);
    u16*   v_ws   = (u16*)walloc((size_t)N * HF_DIM * 2);
    u16*   Bp_ws  = (u16*)walloc((size_t)24 * 16 * 64 * 8 * 2);   // 393 KB
    float* dkp_ws = (float*)walloc((size_t)HF_DIM * NRBF * 4);    // 40 KB
    float* dvp_ws = (float*)walloc((size_t)HF_DIM * NRBF * 4);    // 40 KB
    u16*   msg_ws = (u16*)walloc((size_t)E * HF_DIM * 2);         // 164 MB
    const bool can_split = (ws_size >= off);

    s0_packW<<<768, 256, 0, stream>>>(dW, Bp_ws);
    s1_ln<<<N, 128, 0, stream>>>(s_j, ln_g, ln_b, inp_ws, N);
    s2_qkv_t<<<(N + S2_NT - 1)/S2_NT, 256, 0, stream>>>(
        inp_ws, Wq, bq, Wk, bk, Wv, bv, q_ws, k_ws, v_ws, N);

    if (can_split){
        s0b_packRBF<<<(HF_DIM * NRBF + 255)/256, 256, 0, stream>>>(
            dkW, dvW, dkp_ws, dvp_ws);
        s3a_edge_msg<<<(E + 31)/32, 256, 0, stream>>>(
            dist, nbrs, q_ws, k_ws, v_ws,
            dkp_ws, dkb, dvp_ws, dvb, msg_ws, E, N);
        s3b_dense<<<(E + 31)/32, 512, 0, stream>>>(
            msg_ws, Bp_ws, db, (float*)d_out, E);
    } else {
        s3_fused<<<(E + 31)/32, 256, 0, stream>>>(
            dist, nbrs, q_ws, k_ws, v_ws,
            dkW, dkb, dvW, dvb, Bp_ws, db, (float*)d_out, E, N);
    }
}